// Round 6
// baseline (27.361 us; speedup 1.0000x reference)
//
#include <hip/hip_runtime.h>

#define BB 16
#define NN 65536
#define KK 64
#define TPB 256
#define CHUNK 512                 // two half-chunks of 256 per block
#define NBLK ((BB * NN) / CHUNK)  // 2048 blocks -> 8/CU -> all co-resident

__device__ __forceinline__ float readlane_f(float v, int lane) {
    return __uint_as_float((unsigned)__builtin_amdgcn_readlane((int)__float_as_uint(v), lane));
}

__global__ __launch_bounds__(TPB) void frac_deriv_kernel(
    const float* __restrict__ x,
    const float* __restrict__ loc,
    const float* __restrict__ scale,
    const float* __restrict__ eps,
    const int* __restrict__ lags,
    float* __restrict__ out)
{
    const int tid  = threadIdx.x;
    const int lane = tid & 63;

    // Bijective XCD swizzle (2048 blocks, 256/XCD = 2 rows) + heavy-first.
    const int bid = blockIdx.x;
    const int swz = (bid & 7) * (NBLK / 8) + (bid >> 3);
    const int b   = swz >> 7;
    const int q   = 127 - (swz & 127);
    const int T   = q * CHUNK;

    const float* __restrict__ xr = x + (size_t)b * NN;
    // Issue the xt loads first; their latency hides under the prologue math.
    const float xt0 = xr[T + tid];
    const float xt1 = xr[T + 256 + tid];

    // --- Barrier-free prologue: every wave computes weights + sorts in-register.
    double s  = (double)scale[0];
    double sp = (s > 20.0) ? s : log1p(exp(s));
    double a  = (double)loc[0] + sp * (double)eps[0];
    a = fmin(fmax(a, 0.01), 0.99);
    const double c = a * exp(-lgamma(1.0 - a)) * ((double)(NN - 1) / (double)KK);

    int j = lags[lane];
    j = (j < 1) ? 1 : ((j > NN - 1) ? NN - 1 : j);
    const float w = (float)(c * exp(-(a + 1.0) * log((double)j)));

    // Rank-sort across the wave (ties broken by lane index).
    int rank = 0;
#pragma unroll 8
    for (int k = 0; k < KK; ++k) {
        const int jk = __builtin_amdgcn_readlane(j, k);
        rank += (int)((jk < j) || (jk == j && k < lane));
    }
    // Scatter (push) to rank: lane r ends up holding the r-th smallest lag.
    const int   jv = __builtin_amdgcn_ds_permute(rank << 2, j);
    const float wv = __uint_as_float(
        (unsigned)__builtin_amdgcn_ds_permute(rank << 2, (int)__float_as_uint(w)));

    const int cf = __popcll(__ballot(jv <= T));               // fully-valid prefix
    const int cp = __popcll(__ballot(jv <= T + (CHUNK - 1))); // incl. straddle
    const int cf16 = cf & ~15;

    double acc0 = 0.0, acc1 = 0.0;

    // --- Fully-valid lags: groups of 16, load phase strictly before FMA phase.
    for (int mo = 0; mo < cf16; mo += 16) {
        float v0[16], v1[16];
#pragma unroll
        for (int mi = 0; mi < 16; ++mi) {
            const int jj = __builtin_amdgcn_readlane(jv, mo + mi);
            const float* bp = xr + (T - jj);   // SGPR base, shared vaddr
            v0[mi] = bp[tid];                  // offset:0
            v1[mi] = bp[tid + 256];            // offset:1024
        }
        float g0 = 0.0f, g1 = 0.0f;
#pragma unroll
        for (int mi = 0; mi < 16; ++mi) {
            const float wm = readlane_f(wv, mo + mi);
            g0 = fmaf(xt0 - v0[mi], wm, g0);
            g1 = fmaf(xt1 - v1[mi], wm, g1);
        }
        acc0 += (double)g0;
        acc1 += (double)g1;
    }

    // --- Tail: remainder of valid lags + straddle lags, per-lane masked.
    for (int m = cf16; m < cp; ++m) {
        const int   jj = __builtin_amdgcn_readlane(jv, m);
        const float wm = readlane_f(wv, m);
        const int d0 = T + tid - jj;
        const int d1 = d0 + 256;
        const float g0v = xr[(d0 < 0) ? 0 : d0];
        const float g1v = xr[(d1 < 0) ? 0 : d1];
        acc0 += (d0 >= 0) ? (double)((xt0 - g0v) * wm) : 0.0;
        acc1 += (d1 >= 0) ? (double)((xt1 - g1v) * wm) : 0.0;
    }

    float* __restrict__ orow = out + (size_t)b * NN;
    orow[T + tid]       = (float)acc0;
    orow[T + 256 + tid] = (float)acc1;
}

extern "C" void kernel_launch(void* const* d_in, const int* in_sizes, int n_in,
                              void* d_out, int out_size, void* d_ws, size_t ws_size,
                              hipStream_t stream) {
    const float* x     = (const float*)d_in[0];
    const float* loc   = (const float*)d_in[1];
    const float* scale = (const float*)d_in[2];
    const float* eps   = (const float*)d_in[3];
    const int*   lags  = (const int*)d_in[4];
    float* out = (float*)d_out;

    frac_deriv_kernel<<<NBLK, TPB, 0, stream>>>(x, loc, scale, eps, lags, out);
}

// Round 7
// 18.143 us; speedup vs baseline: 1.5081x; 1.5081x over previous
//
#include <hip/hip_runtime.h>

#define BB 16
#define NN 65536
#define KK 64
#define TPB 256
#define CHUNK 512                 // two half-chunks of 256 per block
#define NBLK ((BB * NN) / CHUNK)  // 2048 blocks

__device__ __forceinline__ float readlane_f(float v, int lane) {
    return __uint_as_float((unsigned)__builtin_amdgcn_readlane((int)__float_as_uint(v), lane));
}

__global__ __launch_bounds__(TPB, 4) void frac_deriv_kernel(
    const float* __restrict__ x,
    const float* __restrict__ loc,
    const float* __restrict__ scale,
    const float* __restrict__ eps,
    const int* __restrict__ lags,
    float* __restrict__ out)
{
    __shared__ int   js_raw[KK];
    __shared__ float ws_raw[KK];
    __shared__ int   js[KK];
    __shared__ float ws[KK];

    const int tid  = threadIdx.x;
    const int lane = tid & 63;

    // Bijective XCD swizzle (2048 blocks, 256/XCD = 2 rows) + heavy-first.
    const int bid = blockIdx.x;
    const int swz = (bid & 7) * (NBLK / 8) + (bid >> 3);
    const int b   = swz >> 7;
    const int q   = 127 - (swz & 127);
    const int T   = q * CHUNK;

    const float* __restrict__ xr = x + (size_t)b * NN;
    // Issue xt loads first; latency hides under the prologue.
    const float xt0 = xr[T + tid];
    const float xt1 = xr[T + 256 + tid];

    // --- Prologue: first wave only computes f64 weights and sorts (cheap per block).
    if (tid < KK) {
        double s  = (double)scale[0];
        double sp = (s > 20.0) ? s : log1p(exp(s));
        double a  = (double)loc[0] + sp * (double)eps[0];
        a = fmin(fmax(a, 0.01), 0.99);
        double c = a * exp(-lgamma(1.0 - a)) * ((double)(NN - 1) / (double)KK);
        int j = lags[tid];
        j = (j < 1) ? 1 : ((j > NN - 1) ? NN - 1 : j);
        js_raw[tid] = j;
        ws_raw[tid] = (float)(c * exp(-(a + 1.0) * log((double)j)));
    }
    __syncthreads();
    if (tid < KK) {
        const int j = js_raw[tid];
        int rank = 0;
        for (int k = 0; k < KK; ++k) {
            const int jk = js_raw[k];
            rank += (int)((jk < j) || (jk == j && k < tid));
        }
        js[rank] = j;
        ws[rank] = ws_raw[tid];
    }
    __syncthreads();

    // Lane-resident sorted copies; each wave ballots its own validity prefix.
    const int   jv = js[lane];
    const float wv = ws[lane];
    const int cf = __popcll(__ballot(jv <= T));               // fully valid
    const int cp = __popcll(__ballot(jv <= T + (CHUNK - 1))); // incl. straddle
    const int cf16 = cf & ~15;

    double acc0 = 0.0, acc1 = 0.0;

    // --- Fully-valid lags: 16-lag groups, strict load phase (32 loads in flight)
    //     then FMA phase; f32 partials flushed to f64 per group.
    for (int mo = 0; mo < cf16; mo += 16) {
        float v0[16], v1[16];
#pragma unroll
        for (int mi = 0; mi < 16; ++mi) {
            const int jj = __builtin_amdgcn_readlane(jv, mo + mi);
            const float* bp = xr + (T - jj);   // SGPR base, vaddr = tid*4 shared
            v0[mi] = bp[tid];                  // offset:0
            v1[mi] = bp[tid + 256];            // offset:1024
        }
        float g0 = 0.0f, g1 = 0.0f;
#pragma unroll
        for (int mi = 0; mi < 16; ++mi) {
            const float wm = readlane_f(wv, mo + mi);
            g0 = fmaf(xt0 - v0[mi], wm, g0);
            g1 = fmaf(xt1 - v1[mi], wm, g1);
        }
        acc0 += (double)g0;
        acc1 += (double)g1;
    }

    // --- Tail: remainder + straddle lags, per-lane masked clamp.
    for (int m = cf16; m < cp; ++m) {
        const int   jj = __builtin_amdgcn_readlane(jv, m);
        const float wm = readlane_f(wv, m);
        const int d0 = T + tid - jj;
        const int d1 = d0 + 256;
        const float g0v = xr[(d0 < 0) ? 0 : d0];
        const float g1v = xr[(d1 < 0) ? 0 : d1];
        acc0 += (d0 >= 0) ? (double)((xt0 - g0v) * wm) : 0.0;
        acc1 += (d1 >= 0) ? (double)((xt1 - g1v) * wm) : 0.0;
    }

    float* __restrict__ orow = out + (size_t)b * NN;
    orow[T + tid]       = (float)acc0;
    orow[T + 256 + tid] = (float)acc1;
}

extern "C" void kernel_launch(void* const* d_in, const int* in_sizes, int n_in,
                              void* d_out, int out_size, void* d_ws, size_t ws_size,
                              hipStream_t stream) {
    const float* x     = (const float*)d_in[0];
    const float* loc   = (const float*)d_in[1];
    const float* scale = (const float*)d_in[2];
    const float* eps   = (const float*)d_in[3];
    const int*   lags  = (const int*)d_in[4];
    float* out = (float*)d_out;

    frac_deriv_kernel<<<NBLK, TPB, 0, stream>>>(x, loc, scale, eps, lags, out);
}

// Round 8
// 16.606 us; speedup vs baseline: 1.6477x; 1.0926x over previous
//
#include <hip/hip_runtime.h>

#define BB 16
#define NN 65536
#define KK 64
#define TPB 256
#define EPB 1024                  // elements per block (4 per thread, one float4)
#define NBLK ((BB * NN) / EPB)    // 1024 blocks = 4/CU, all co-resident

__device__ __forceinline__ float readlane_f(float v, int lane) {
    return __uint_as_float((unsigned)__builtin_amdgcn_readlane((int)__float_as_uint(v), lane));
}

__device__ __forceinline__ float4 load4(const float* p) {
    float4 v;
    __builtin_memcpy(&v, p, 16);   // lowers to global_load_dwordx4 (align-4 ok on gfx9+)
    return v;
}

__global__ __launch_bounds__(TPB) void frac_deriv_kernel(
    const float* __restrict__ x,
    const float* __restrict__ loc,
    const float* __restrict__ scale,
    const float* __restrict__ eps,
    const int* __restrict__ lags,
    float* __restrict__ out)
{
    __shared__ int   js_raw[KK];
    __shared__ float ws_raw[KK];
    __shared__ int   js[KK];
    __shared__ float ws[KK];

    const int tid  = threadIdx.x;
    const int lane = tid & 63;

    // Bijective XCD swizzle: 1024 blocks -> 128/XCD = 2 rows per XCD L2.
    const int bid = blockIdx.x;
    const int swz = (bid & 7) * (NBLK / 8) + (bid >> 3);
    const int b   = swz >> 6;          // row [0,16)
    const int q   = swz & 63;          // segment within row
    const int T   = q * EPB;

    const float* __restrict__ xr = x + (size_t)b * NN;
    const int e0 = T + 4 * tid;        // this thread's first element (16B aligned)
    const float4 xt = load4(xr + e0);  // issue early; hides under prologue

    // --- Prologue: wave 0 computes f64 weights and rank-sorts lags.
    if (tid < KK) {
        double s  = (double)scale[0];
        double sp = (s > 20.0) ? s : log1p(exp(s));
        double a  = (double)loc[0] + sp * (double)eps[0];
        a = fmin(fmax(a, 0.01), 0.99);
        double c = a * exp(-lgamma(1.0 - a)) * ((double)(NN - 1) / (double)KK);
        int j = lags[tid];
        j = (j < 1) ? 1 : ((j > NN - 1) ? NN - 1 : j);
        js_raw[tid] = j;
        ws_raw[tid] = (float)(c * exp(-(a + 1.0) * log((double)j)));
    }
    __syncthreads();
    if (tid < KK) {
        const int j = js_raw[tid];
        int rank = 0;
        for (int k = 0; k < KK; ++k) {
            const int jk = js_raw[k];
            rank += (int)((jk < j) || (jk == j && k < tid));
        }
        js[rank] = j;
        ws[rank] = ws_raw[tid];
    }
    __syncthreads();

    // Lane-resident sorted lags/weights; per-wave validity prefixes via ballot.
    const int   jv = js[lane];
    const float wv = ws[lane];
    const int cf = __popcll(__ballot(jv <= T));             // valid for whole block
    const int cp = __popcll(__ballot(jv <= T + (EPB - 1))); // incl. straddle
    const int cf8 = cf & ~7;

    double a0 = 0.0, a1 = 0.0, a2 = 0.0, a3 = 0.0;

    // --- Fully-valid lags: ONE dwordx4 gather per lag per wave.
    for (int mo = 0; mo < cf8; mo += 8) {
        float4 g = make_float4(0.f, 0.f, 0.f, 0.f);
#pragma unroll
        for (int mi = 0; mi < 8; ++mi) {
            const int   m  = mo + mi;
            const int   jj = __builtin_amdgcn_readlane(jv, m);
            const float w  = readlane_f(wv, m);
            const float4 xg = load4(xr + (e0 - jj));   // SGPR base + shared voffset
            g.x = fmaf(xt.x - xg.x, w, g.x);
            g.y = fmaf(xt.y - xg.y, w, g.y);
            g.z = fmaf(xt.z - xg.z, w, g.z);
            g.w = fmaf(xt.w - xg.w, w, g.w);
        }
        a0 += (double)g.x; a1 += (double)g.y; a2 += (double)g.z; a3 += (double)g.w;
    }
    // Remainder of fully-valid lags.
    for (int m = cf8; m < cf; ++m) {
        const int   jj = __builtin_amdgcn_readlane(jv, m);
        const float w  = readlane_f(wv, m);
        const float4 xg = load4(xr + (e0 - jj));
        a0 += (double)((xt.x - xg.x) * w);
        a1 += (double)((xt.y - xg.y) * w);
        a2 += (double)((xt.z - xg.z) * w);
        a3 += (double)((xt.w - xg.w) * w);
    }
    // Straddle lags (T < j <= T+EPB-1): per-element masked clamp (~1 lag typical).
    for (int m = cf; m < cp; ++m) {
        const int   jj = __builtin_amdgcn_readlane(jv, m);
        const float w  = readlane_f(wv, m);
        const int d0 = e0 - jj;
        const float g0 = xr[(d0     < 0) ? 0 : d0];
        const float g1 = xr[(d0 + 1 < 0) ? 0 : d0 + 1];
        const float g2 = xr[(d0 + 2 < 0) ? 0 : d0 + 2];
        const float g3 = xr[(d0 + 3 < 0) ? 0 : d0 + 3];
        a0 += (d0     >= 0) ? (double)((xt.x - g0) * w) : 0.0;
        a1 += (d0 + 1 >= 0) ? (double)((xt.y - g1) * w) : 0.0;
        a2 += (d0 + 2 >= 0) ? (double)((xt.z - g2) * w) : 0.0;
        a3 += (d0 + 3 >= 0) ? (double)((xt.w - g3) * w) : 0.0;
    }

    float4 r = make_float4((float)a0, (float)a1, (float)a2, (float)a3);
    __builtin_memcpy(out + (size_t)b * NN + e0, &r, 16);   // aligned dwordx4 store
}

extern "C" void kernel_launch(void* const* d_in, const int* in_sizes, int n_in,
                              void* d_out, int out_size, void* d_ws, size_t ws_size,
                              hipStream_t stream) {
    const float* x     = (const float*)d_in[0];
    const float* loc   = (const float*)d_in[1];
    const float* scale = (const float*)d_in[2];
    const float* eps   = (const float*)d_in[3];
    const int*   lags  = (const int*)d_in[4];
    float* out = (float*)d_out;

    frac_deriv_kernel<<<NBLK, TPB, 0, stream>>>(x, loc, scale, eps, lags, out);
}